// Round 2
// baseline (237.983 us; speedup 1.0000x reference)
//
#include <hip/hip_runtime.h>
#include <math.h>

// Problem constants
#define N   512   // memory units == batch
#define M   256   // memory unit size
#define A   128   // action size
#define HS  512   // hidden size
#define C   512   // controller size

// ---------------- workspace layout (floats) ----------------
// GI region (3 MB) is dead after k_act -> reused for sim partial-2 buffers.
// CIRC region written only by k_circ (after all heads consumers) -> holds heads partial-2.
#define WS_GI      0          // [512*1536] GRU pre-activation accumulator (zeroed, atomics)
#define WS_SIMR2   0          // [512*512]  sim read partial 2 (aliases GI, written after k_act)
#define WS_SIMW2   262144     // [512*512]  sim write partial 2 (aliases GI)
#define WS_H       786432     // [512*512]  controller output h
#define WS_HEADS   1048576    // [512*1024] partial 1 (K 0..255, bias included)
#define WS_SIMR    1572864    // [512*512]  sim read partial 1
#define WS_SIMW    1835008    // [512*512]  sim write partial 1
#define WS_SHIFT   2097152    // [512*512]  shift softmax (natural layout [B][N])
#define WS_WGRT    2359296    // [512*512]  transposed gated read weight
#define WS_WGWT    2621440
#define WS_SHIFTT  2883584
#define WS_CIRCTR  3145728    // circ+sharpen result transposed [b][i] (unnormalized p)
#define WS_CIRCTW  3407872
#define WS_HEADS2  3145728    // [512*1024] heads partial 2 (K 256..511) — aliases CIRC region
#define WS_G       3670016    // [512] gate
#define WS_GAMMA   3670528    // [512]
#define WS_INVM    3671040    // [512] 1/(||mem_i||+1e-16)
#define WS_INVKR   3671552    // [512]
#define WS_INVKW   3672064    // [512]
#define WS_CSR     3672576    // [512] sharpen row sums (read)
#define WS_CSW     3673088    // [512]

// ---------------- shared GEMM staging helpers ----------------
// Load a 32x32 tile from row-major src (row stride ld), store TRANSPOSED into lds[k*36 + row].
__device__ __forceinline__ void stage32x32T(const float* __restrict__ src, int ld,
                                            float* __restrict__ lds, int tid) {
#pragma unroll
  for (int l = 0; l < 4; ++l) {
    int e = tid * 4 + l * 256;
    int row = e >> 5;
    int k = e & 31;
    const float4 v = *reinterpret_cast<const float4*>(src + row * ld + k);
    lds[(k + 0) * 36 + row] = v.x;
    lds[(k + 1) * 36 + row] = v.y;
    lds[(k + 2) * 36 + row] = v.z;
    lds[(k + 3) * 36 + row] = v.w;
  }
}

// Same, but element-wise sum of two sources (for split-K partial combination).
__device__ __forceinline__ void stage32x32T_sum2(const float* __restrict__ s1,
                                                 const float* __restrict__ s2, int ld,
                                                 float* __restrict__ lds, int tid) {
#pragma unroll
  for (int l = 0; l < 4; ++l) {
    int e = tid * 4 + l * 256;
    int row = e >> 5;
    int k = e & 31;
    const float4 v = *reinterpret_cast<const float4*>(s1 + row * ld + k);
    const float4 w = *reinterpret_cast<const float4*>(s2 + row * ld + k);
    lds[(k + 0) * 36 + row] = v.x + w.x;
    lds[(k + 1) * 36 + row] = v.y + w.y;
    lds[(k + 2) * 36 + row] = v.z + w.z;
    lds[(k + 3) * 36 + row] = v.w + w.w;
  }
}

// Load a 32x32 tile, keep natural layout lds[row*36 + col].
__device__ __forceinline__ void stage32x32N(const float* __restrict__ src, int ld,
                                            float* __restrict__ lds, int tid) {
#pragma unroll
  for (int l = 0; l < 4; ++l) {
    int e = tid * 4 + l * 256;
    int row = e >> 5;
    int col = e & 31;
    float4 v = *reinterpret_cast<const float4*>(src + row * ld + col);
    *reinterpret_cast<float4*>(&lds[row * 36 + col]) = v;
  }
}

// ---------------- 1. GRU GEMM (split-K=5, atomic) ----------------
// gi[b, g*512 + c] += sum_k x[b,k] * W_ih[g*512+c, k]   (x = concat(action, hidden))
// 1280 blocks = 5 waves/CU; A-tile shared across 3 gates -> 64 B/lane LDS per 48 FMA (not LDS-bound).
__global__ __launch_bounds__(64) void k_gru(const float* __restrict__ action,
                                            const float* __restrict__ hidden,
                                            const float* __restrict__ W_ih,
                                            float* __restrict__ gi) {
  __shared__ float As[32 * 36];
  __shared__ float Ws[3][32 * 36];
  const int tid = threadIdx.x;
  const int bi = blockIdx.x;   // b tile
  const int bn = blockIdx.y;   // c tile
  const int kz = blockIdx.z;   // k split 0..4, each 128 wide
  const float* xsrc;
  int xld;
  if (kz == 0) { xsrc = action; xld = A; }
  else { xsrc = hidden + (kz - 1) * 128; xld = HS; }

  const int r0 = (tid >> 3) * 4, c0 = (tid & 7) * 4;
  float acc[3][4][4] = {};

  for (int kt = 0; kt < 4; ++kt) {
    const int k0 = kt * 32;
    __syncthreads();
    stage32x32T(xsrc + (bi * 32) * xld + k0, xld, As, tid);
#pragma unroll
    for (int g = 0; g < 3; ++g)
      stage32x32T(W_ih + (g * 512 + bn * 32) * 640 + kz * 128 + k0, 640, Ws[g], tid);
    __syncthreads();
#pragma unroll
    for (int kk = 0; kk < 32; ++kk) {
      const float4 a = *reinterpret_cast<const float4*>(&As[kk * 36 + r0]);
      const float av[4] = {a.x, a.y, a.z, a.w};
#pragma unroll
      for (int g = 0; g < 3; ++g) {
        const float4 b = *reinterpret_cast<const float4*>(&Ws[g][kk * 36 + c0]);
        const float bv[4] = {b.x, b.y, b.z, b.w};
#pragma unroll
        for (int i = 0; i < 4; ++i)
#pragma unroll
          for (int j = 0; j < 4; ++j)
            acc[g][i][j] = fmaf(av[i], bv[j], acc[g][i][j]);
      }
    }
  }
#pragma unroll
  for (int g = 0; g < 3; ++g)
#pragma unroll
    for (int i = 0; i < 4; ++i)
#pragma unroll
      for (int j = 0; j < 4; ++j)
        atomicAdd(&gi[(bi * 32 + r0 + i) * 1536 + g * 512 + bn * 32 + c0 + j], acc[g][i][j]);
}

// ---------------- 2. GRU activation (float4) ----------------
__global__ __launch_bounds__(256) void k_act(const float* __restrict__ gi,
                                             const float* __restrict__ b_ih,
                                             const float* __restrict__ b_hh,
                                             float* __restrict__ h) {
  const int idx = blockIdx.x * 256 + threadIdx.x;   // 65536 threads, 4 elems each
  const int b = idx >> 7, c4 = (idx & 127) * 4;
  const float4 g0 = *reinterpret_cast<const float4*>(gi + b * 1536 + c4);
  const float4 g1 = *reinterpret_cast<const float4*>(gi + b * 1536 + 512 + c4);
  const float4 g2 = *reinterpret_cast<const float4*>(gi + b * 1536 + 1024 + c4);
  const float4 bi0 = *reinterpret_cast<const float4*>(b_ih + c4);
  const float4 bi1 = *reinterpret_cast<const float4*>(b_ih + 512 + c4);
  const float4 bi2 = *reinterpret_cast<const float4*>(b_ih + 1024 + c4);
  const float4 bh0 = *reinterpret_cast<const float4*>(b_hh + c4);
  const float4 bh1 = *reinterpret_cast<const float4*>(b_hh + 512 + c4);
  const float4 bh2 = *reinterpret_cast<const float4*>(b_hh + 1024 + c4);
  float4 out;
  const float gr[4] = {g0.x + bi0.x + bh0.x, g0.y + bi0.y + bh0.y, g0.z + bi0.z + bh0.z, g0.w + bi0.w + bh0.w};
  const float gz[4] = {g1.x + bi1.x + bh1.x, g1.y + bi1.y + bh1.y, g1.z + bi1.z + bh1.z, g1.w + bi1.w + bh1.w};
  const float gn[4] = {g2.x + bi2.x, g2.y + bi2.y, g2.z + bi2.z, g2.w + bi2.w};
  const float hn[4] = {bh2.x, bh2.y, bh2.z, bh2.w};
  float res[4];
#pragma unroll
  for (int u = 0; u < 4; ++u) {
    const float r = 1.0f / (1.0f + expf(-gr[u]));
    const float z = 1.0f / (1.0f + expf(-gz[u]));
    const float n = tanhf(gn[u] + r * hn[u]);
    res[u] = (1.0f - z) * n;
  }
  out.x = res[0]; out.y = res[1]; out.z = res[2]; out.w = res[3];
  *reinterpret_cast<float4*>(h + b * 512 + c4) = out;
}

// ---------------- 3. heads GEMM (split-K=2): read_key | write_key | shift logits ----------------
// kz=0 -> heads1 (K 0..255, + bias); kz=1 -> heads2 (K 256..511). Consumers sum.
__global__ __launch_bounds__(64) void k_heads(const float* __restrict__ h,
                                              const float* __restrict__ W_read, const float* __restrict__ b_read,
                                              const float* __restrict__ W_write, const float* __restrict__ b_write,
                                              const float* __restrict__ W_shift, const float* __restrict__ b_shift,
                                              float* __restrict__ heads1, float* __restrict__ heads2) {
  __shared__ float As[32 * 36];
  __shared__ float Bs[32 * 36];
  const int tid = threadIdx.x;
  const int bi = blockIdx.x;       // b rows
  const int n0 = blockIdx.y * 32;  // output cols (0..1023)
  const int kz = blockIdx.z;       // K split (0..1), 256 wide
  const float* W;
  const float* bias;
  if (n0 < 256) { W = W_read + n0 * 512; bias = b_read + n0; }
  else if (n0 < 512) { W = W_write + (n0 - 256) * 512; bias = b_write + (n0 - 256); }
  else { W = W_shift + (n0 - 512) * 512; bias = b_shift + (n0 - 512); }

  const int r0 = (tid >> 3) * 4, c0 = (tid & 7) * 4;
  float acc[4][4] = {};
  for (int kt = 0; kt < 8; ++kt) {
    const int k0 = kz * 256 + kt * 32;
    __syncthreads();
    stage32x32T(h + (bi * 32) * 512 + k0, 512, As, tid);
    stage32x32T(W + k0, 512, Bs, tid);
    __syncthreads();
#pragma unroll
    for (int kk = 0; kk < 32; ++kk) {
      const float4 a = *reinterpret_cast<const float4*>(&As[kk * 36 + r0]);
      const float4 b = *reinterpret_cast<const float4*>(&Bs[kk * 36 + c0]);
      const float av[4] = {a.x, a.y, a.z, a.w};
      const float bv[4] = {b.x, b.y, b.z, b.w};
#pragma unroll
      for (int i = 0; i < 4; ++i)
#pragma unroll
        for (int j = 0; j < 4; ++j)
          acc[i][j] = fmaf(av[i], bv[j], acc[i][j]);
    }
  }
  float* out = kz ? heads2 : heads1;
#pragma unroll
  for (int i = 0; i < 4; ++i)
#pragma unroll
    for (int j = 0; j < 4; ++j)
      out[(bi * 32 + r0 + i) * 1024 + n0 + c0 + j] = acc[i][j] + (kz ? 0.0f : bias[c0 + j]);
}

// ---------------- 4. gate/gamma + inverse norms (merged) ----------------
__global__ __launch_bounds__(64) void k_ggnorms(const float* __restrict__ h,
                                                const float* __restrict__ W_gate, const float* __restrict__ b_gate,
                                                const float* __restrict__ W_gamma, const float* __restrict__ b_gamma,
                                                const float* __restrict__ memory,
                                                const float* __restrict__ heads1, const float* __restrict__ heads2,
                                                float* __restrict__ g, float* __restrict__ gamma,
                                                float* __restrict__ invm, float* __restrict__ invkr,
                                                float* __restrict__ invkw) {
  const int r = blockIdx.x, t = threadIdx.x;
  if (r < 512) {
    // gate & gamma for batch row r
    float ag = 0.f, am = 0.f;
#pragma unroll
    for (int u = 0; u < 8; ++u) {
      const float hv = h[r * 512 + t + 64 * u];
      ag = fmaf(hv, W_gate[t + 64 * u], ag);
      am = fmaf(hv, W_gamma[t + 64 * u], am);
    }
    for (int o = 32; o > 0; o >>= 1) { ag += __shfl_down(ag, o); am += __shfl_down(am, o); }
    if (t == 0) {
      g[r] = 1.0f / (1.0f + expf(-(ag + b_gate[0])));
      const float x = am + b_gamma[0];
      gamma[r] = (x > 0.f) ? (x + log1pf(expf(-x))) : log1pf(expf(x));
    }
    return;
  }
  // norms
  float ss;
  float* dst;
  if (r < 1024) {
    const float4 v = *reinterpret_cast<const float4*>(memory + (r - 512) * 256 + t * 4);
    ss = v.x * v.x + v.y * v.y + v.z * v.z + v.w * v.w;
    dst = invm + (r - 512);
  } else {
    const int row = (r < 1536) ? (r - 1024) : (r - 1536);
    const int seg = (r < 1536) ? 0 : 256;
    const float4 v = *reinterpret_cast<const float4*>(heads1 + row * 1024 + seg + t * 4);
    const float4 w = *reinterpret_cast<const float4*>(heads2 + row * 1024 + seg + t * 4);
    const float a0 = v.x + w.x, a1 = v.y + w.y, a2 = v.z + w.z, a3 = v.w + w.w;
    ss = a0 * a0 + a1 * a1 + a2 * a2 + a3 * a3;
    dst = ((r < 1536) ? invkr : invkw) + row;
  }
  for (int o = 32; o > 0; o >>= 1) ss += __shfl_down(ss, o);
  if (t == 0) *dst = 1.0f / (sqrtf(ss) + 1e-16f);
}

// ---------------- 5. similarity GEMM (split-K=2, raw dots) ----------------
// z: bit0 = gemm (read/write), bit1 = K split. Partials summed in k_rowsoft.
__global__ __launch_bounds__(64) void k_sim(const float* __restrict__ memory,
                                            const float* __restrict__ heads1, const float* __restrict__ heads2,
                                            float* __restrict__ simR1, float* __restrict__ simW1,
                                            float* __restrict__ simR2, float* __restrict__ simW2) {
  __shared__ float As[32 * 36];
  __shared__ float Bs[32 * 36];
  const int tid = threadIdx.x;
  const int bi = blockIdx.x;            // i tile (memory rows)
  const int bn = blockIdx.y;            // b tile (key rows)
  const int gemm = blockIdx.z & 1;
  const int kz = blockIdx.z >> 1;       // K split (0..1), 128 wide
  const int seg = gemm ? 256 : 0;
  float* out = kz ? (gemm ? simW2 : simR2) : (gemm ? simW1 : simR1);

  const int r0 = (tid >> 3) * 4, c0 = (tid & 7) * 4;
  float acc[4][4] = {};
  for (int kt = 0; kt < 4; ++kt) {
    const int k0 = kz * 128 + kt * 32;
    __syncthreads();
    stage32x32T(memory + (bi * 32) * 256 + k0, 256, As, tid);
    stage32x32T_sum2(heads1 + (bn * 32) * 1024 + seg + k0,
                     heads2 + (bn * 32) * 1024 + seg + k0, 1024, Bs, tid);
    __syncthreads();
#pragma unroll
    for (int kk = 0; kk < 32; ++kk) {
      const float4 a = *reinterpret_cast<const float4*>(&As[kk * 36 + r0]);
      const float4 b = *reinterpret_cast<const float4*>(&Bs[kk * 36 + c0]);
      const float av[4] = {a.x, a.y, a.z, a.w};
      const float bv[4] = {b.x, b.y, b.z, b.w};
#pragma unroll
      for (int i = 0; i < 4; ++i)
#pragma unroll
        for (int j = 0; j < 4; ++j)
          acc[i][j] = fmaf(av[i], bv[j], acc[i][j]);
    }
  }
#pragma unroll
  for (int i = 0; i < 4; ++i)
#pragma unroll
    for (int j = 0; j < 4; ++j)
      out[(bi * 32 + r0 + i) * 512 + bn * 32 + c0 + j] = acc[i][j];
}

// ---------------- 6. row softmax (+cosine scale, +gate mix) / shift softmax ----------------
__global__ __launch_bounds__(256) void k_rowsoft(const float* __restrict__ simR1, const float* __restrict__ simW1,
                                                 const float* __restrict__ simR2, const float* __restrict__ simW2,
                                                 const float* __restrict__ heads1, const float* __restrict__ heads2,
                                                 const float* __restrict__ invm, const float* __restrict__ invkr,
                                                 const float* __restrict__ invkw, const float* __restrict__ g,
                                                 const float* __restrict__ prevR, const float* __restrict__ prevW,
                                                 float* __restrict__ wgr, float* __restrict__ wgw,
                                                 float* __restrict__ shift_nat) {
  __shared__ float red[8];
  const int row = blockIdx.x, mode = blockIdx.y, t = threadIdx.x;
  float v0, v1;
  if (mode == 2) {
    const float2 s1 = *reinterpret_cast<const float2*>(heads1 + row * 1024 + 512 + 2 * t);
    const float2 s2 = *reinterpret_cast<const float2*>(heads2 + row * 1024 + 512 + 2 * t);
    v0 = s1.x + s2.x; v1 = s1.y + s2.y;
  } else {
    const float* sA = mode ? simW1 : simR1;
    const float* sB = mode ? simW2 : simR2;
    const float* invk = mode ? invkw : invkr;
    const float2 a = *reinterpret_cast<const float2*>(sA + row * 512 + 2 * t);
    const float2 b = *reinterpret_cast<const float2*>(sB + row * 512 + 2 * t);
    const float sc = invm[row];
    v0 = (a.x + b.x) * sc * invk[2 * t];
    v1 = (a.y + b.y) * sc * invk[2 * t + 1];
  }
  float m = fmaxf(v0, v1);
  for (int o = 32; o > 0; o >>= 1) m = fmaxf(m, __shfl_down(m, o));
  if ((t & 63) == 0) red[t >> 6] = m;
  __syncthreads();
  m = fmaxf(fmaxf(red[0], red[1]), fmaxf(red[2], red[3]));
  const float e0 = expf(v0 - m), e1 = expf(v1 - m);
  float s2 = e0 + e1;
  for (int o = 32; o > 0; o >>= 1) s2 += __shfl_down(s2, o);
  if ((t & 63) == 0) red[4 + (t >> 6)] = s2;
  __syncthreads();
  const float S = (red[4] + red[5]) + (red[6] + red[7]);
  const float inv = 1.0f / S;
  const float p0 = e0 * inv, p1 = e1 * inv;
  if (mode == 2) {
    *reinterpret_cast<float2*>(shift_nat + row * 512 + 2 * t) = make_float2(p0, p1);
  } else {
    const float* prev = mode ? prevW : prevR;
    float* outw = mode ? wgw : wgr;
    const float gv = g[row];
    const float2 pr = *reinterpret_cast<const float2*>(prev + row * 512 + 2 * t);
    *reinterpret_cast<float2*>(outw + row * 512 + 2 * t) =
        make_float2(gv * p0 + (1.0f - gv) * pr.x, gv * p1 + (1.0f - gv) * pr.y);
  }
}

// ---------------- 7. transposes (wgr, wgw, shift) ----------------
__global__ __launch_bounds__(256) void k_transpose(const float* __restrict__ wgr, const float* __restrict__ wgw,
                                                   const float* __restrict__ shift_nat,
                                                   float* __restrict__ wgrT, float* __restrict__ wgwT,
                                                   float* __restrict__ shiftT) {
  __shared__ float tile[32][33];
  const int z = blockIdx.z;
  const float* src = (z == 0) ? wgr : (z == 1) ? wgw : shift_nat;
  float* dst = (z == 0) ? wgrT : (z == 1) ? wgwT : shiftT;
  const int bx = blockIdx.x, by = blockIdx.y, tx = threadIdx.x, ty = threadIdx.y;
#pragma unroll
  for (int k2 = 0; k2 < 4; ++k2)
    tile[ty + 8 * k2][tx] = src[(by * 32 + ty + 8 * k2) * 512 + bx * 32 + tx];
  __syncthreads();
#pragma unroll
  for (int k2 = 0; k2 < 4; ++k2)
    dst[(bx * 32 + ty + 8 * k2) * 512 + by * 32 + tx] = tile[tx][ty + 8 * k2];
}

// ---------------- 8. circular convolution + fused sharpen ----------------
// out[b,i] = (sum_j w[b,(i-j)&511] * s[b,j]) ^ gamma[i];  csum[b] = sum_i out[b,i]
__global__ __launch_bounds__(256) void k_circ(const float* __restrict__ wgrT, const float* __restrict__ wgwT,
                                              const float* __restrict__ shiftT,
                                              const float* __restrict__ gamma,
                                              float* __restrict__ circTR, float* __restrict__ circTW,
                                              float* __restrict__ csumR, float* __restrict__ csumW) {
  __shared__ float ls[4][1600];  // per wave: [0..1055] swizzled doubled w, [1056..1567] s
  const int wid = threadIdx.x >> 6, lane = threadIdx.x & 63;
  const int b = blockIdx.x * 4 + wid;
  const float* wsrc = (blockIdx.y ? wgwT : wgrT) + b * 512;
  const float* ssrc = shiftT + b * 512;
  float* out = (blockIdx.y ? circTW : circTR) + b * 512;
  float* cs = blockIdx.y ? csumW : csumR;
  float* wl = ls[wid];
  float* sl = ls[wid] + 1056;

#pragma unroll
  for (int u = 0; u < 8; ++u) {
    const int k = lane + 64 * u;
    const float v = wsrc[k];
    wl[k + (k >> 5)] = v;             // swizzle: addr + addr/32 spreads stride-8 reads over banks
    const int k2 = k + 512;
    wl[k2 + (k2 >> 5)] = v;
    sl[k] = ssrc[k];
  }
  __syncthreads();

  const int i0 = lane * 8;
  float acc[8] = {};
  float win[8];
#pragma unroll
  for (int q = 0; q < 8; ++q) {
    const int a0 = i0 + 512 + q;
    win[q] = wl[a0 + (a0 >> 5)];
  }
  for (int jb = 0; jb < 512; jb += 8) {
    const float4 sA = *reinterpret_cast<const float4*>(&sl[jb]);
    const float4 sB = *reinterpret_cast<const float4*>(&sl[jb + 4]);
    const float sv[8] = {sA.x, sA.y, sA.z, sA.w, sB.x, sB.y, sB.z, sB.w};
#pragma unroll
    for (int u = 0; u < 8; ++u) {
      const float s = sv[u];
#pragma unroll
      for (int t = 0; t < 8; ++t) acc[t] = fmaf(win[(t - u) & 7], s, acc[t]);
      const int na = i0 + 511 - (jb + u);
      win[(7 - u) & 7] = wl[na + (na >> 5)];
    }
  }
  // fused sharpen: p = acc ^ gamma[i], row-sum over i (per wave = per row b)
  const float4 gm0 = *reinterpret_cast<const float4*>(gamma + i0);
  const float4 gm1 = *reinterpret_cast<const float4*>(gamma + i0 + 4);
  const float ge[8] = {gm0.x, gm0.y, gm0.z, gm0.w, gm1.x, gm1.y, gm1.z, gm1.w};
  float p[8];
  float local = 0.f;
#pragma unroll
  for (int q = 0; q < 8; ++q) { p[q] = powf(acc[q], ge[q]); local += p[q]; }
  *reinterpret_cast<float4*>(out + i0) = make_float4(p[0], p[1], p[2], p[3]);
  *reinterpret_cast<float4*>(out + i0 + 4) = make_float4(p[4], p[5], p[6], p[7]);
  for (int o = 32; o > 0; o >>= 1) local += __shfl_down(local, o);
  if (lane == 0) cs[b] = local;
}

// ---------------- 9. final weights: out[i,b] = p[b,i]/csum[b] (transpose-divide) ----------------
__global__ __launch_bounds__(256) void k_finalw(const float* __restrict__ circTR, const float* __restrict__ circTW,
                                                const float* __restrict__ csumR, const float* __restrict__ csumW,
                                                float* __restrict__ d_out) {
  __shared__ float tile[32][33];
  const int z = blockIdx.z;
  const float* src = z ? circTW : circTR;
  const float* cs = z ? csumW : csumR;
  float* dst = d_out + 131072 + z * 262144;
  const int bx = blockIdx.x, by = blockIdx.y, tx = threadIdx.x, ty = threadIdx.y;
#pragma unroll
  for (int k2 = 0; k2 < 4; ++k2) {
    const int r = by * 32 + ty + 8 * k2;
    tile[ty + 8 * k2][tx] = src[r * 512 + bx * 32 + tx] * (1.0f / cs[r]);
  }
  __syncthreads();
#pragma unroll
  for (int k2 = 0; k2 < 4; ++k2)
    dst[(bx * 32 + ty + 8 * k2) * 512 + by * 32 + tx] = tile[tx][ty + 8 * k2];
}

// ---------------- 10. read vector (split-K=4, atomic into zeroed d_out) ----------------
// rv[i,m] = sum_b (p[b,i]/csum[b]) * memory[b,m]
__global__ __launch_bounds__(64) void k_readvec(const float* __restrict__ circTR, const float* __restrict__ csumR,
                                                const float* __restrict__ memory, float* __restrict__ rv) {
  __shared__ float As[32 * 36];  // [k][i]
  __shared__ float Bs[32 * 36];  // [k][m]
  const int tid = threadIdx.x;
  const int bi = blockIdx.x;  // i tile (16)
  const int bm = blockIdx.y;  // m tile (8)
  const int kz = blockIdx.z;  // K split (0..3), 128 wide
  const int r0 = (tid >> 3) * 4, c0 = (tid & 7) * 4;
  float acc[4][4] = {};
  for (int kt = 0; kt < 4; ++kt) {
    const int k0 = kz * 128 + kt * 32;
    __syncthreads();
    // stage A rows with per-row 1/csum scale
#pragma unroll
    for (int l = 0; l < 4; ++l) {
      const int e = tid * 4 + l * 256;
      const int row = e >> 5, col = e & 31;
      float4 v = *reinterpret_cast<const float4*>(circTR + (k0 + row) * 512 + bi * 32 + col);
      const float rs = 1.0f / csumR[k0 + row];
      v.x *= rs; v.y *= rs; v.z *= rs; v.w *= rs;
      *reinterpret_cast<float4*>(&As[row * 36 + col]) = v;
    }
    stage32x32N(memory + k0 * 256 + bm * 32, 256, Bs, tid);
    __syncthreads();
#pragma unroll
    for (int kk = 0; kk < 32; ++kk) {
      const float4 a = *reinterpret_cast<const float4*>(&As[kk * 36 + r0]);
      const float4 b = *reinterpret_cast<const float4*>(&Bs[kk * 36 + c0]);
      const float av[4] = {a.x, a.y, a.z, a.w};
      const float bv[4] = {b.x, b.y, b.z, b.w};
#pragma unroll
      for (int i = 0; i < 4; ++i)
#pragma unroll
        for (int j = 0; j < 4; ++j)
          acc[i][j] = fmaf(av[i], bv[j], acc[i][j]);
    }
  }
#pragma unroll
  for (int i = 0; i < 4; ++i)
#pragma unroll
    for (int j = 0; j < 4; ++j)
      atomicAdd(&rv[(bi * 32 + r0 + i) * 256 + bm * 32 + c0 + j], acc[i][j]);
}

// ---------------- launcher ----------------
extern "C" void kernel_launch(void* const* d_in, const int* in_sizes, int n_in,
                              void* d_out, int out_size, void* d_ws, size_t ws_size,
                              hipStream_t stream) {
  const float* action  = (const float*)d_in[0];
  const float* hidden  = (const float*)d_in[1];
  const float* prevR   = (const float*)d_in[2];
  const float* prevW   = (const float*)d_in[3];
  const float* memory  = (const float*)d_in[4];
  const float* W_ih    = (const float*)d_in[5];
  // d_in[6] = W_hh — unused (h0 == 0)
  const float* b_ih    = (const float*)d_in[7];
  const float* b_hh    = (const float*)d_in[8];
  const float* W_read  = (const float*)d_in[9];
  const float* b_read  = (const float*)d_in[10];
  const float* W_write = (const float*)d_in[11];
  const float* b_write = (const float*)d_in[12];
  const float* W_shift = (const float*)d_in[13];
  const float* b_shift = (const float*)d_in[14];
  const float* W_gamma = (const float*)d_in[15];
  const float* b_gamma = (const float*)d_in[16];
  const float* W_gate  = (const float*)d_in[17];
  const float* b_gate  = (const float*)d_in[18];

  float* ws = (float*)d_ws;
  float* out = (float*)d_out;

  // zero the GRU split-K accumulator and the read_vector output (atomic targets)
  hipMemsetAsync(ws + WS_GI, 0, 512 * 1536 * sizeof(float), stream);
  hipMemsetAsync(out, 0, 512 * 256 * sizeof(float), stream);

  k_gru<<<dim3(16, 16, 5), 64, 0, stream>>>(action, hidden, W_ih, ws + WS_GI);
  k_act<<<256, 256, 0, stream>>>(ws + WS_GI, b_ih, b_hh, ws + WS_H);
  k_heads<<<dim3(16, 32, 2), 64, 0, stream>>>(ws + WS_H, W_read, b_read, W_write, b_write,
                                              W_shift, b_shift, ws + WS_HEADS, ws + WS_HEADS2);
  k_ggnorms<<<2048, 64, 0, stream>>>(ws + WS_H, W_gate, b_gate, W_gamma, b_gamma,
                                     memory, ws + WS_HEADS, ws + WS_HEADS2,
                                     ws + WS_G, ws + WS_GAMMA,
                                     ws + WS_INVM, ws + WS_INVKR, ws + WS_INVKW);
  k_sim<<<dim3(16, 16, 4), 64, 0, stream>>>(memory, ws + WS_HEADS, ws + WS_HEADS2,
                                            ws + WS_SIMR, ws + WS_SIMW, ws + WS_SIMR2, ws + WS_SIMW2);
  k_rowsoft<<<dim3(512, 3), 256, 0, stream>>>(ws + WS_SIMR, ws + WS_SIMW, ws + WS_SIMR2, ws + WS_SIMW2,
                                              ws + WS_HEADS, ws + WS_HEADS2,
                                              ws + WS_INVM, ws + WS_INVKR, ws + WS_INVKW,
                                              ws + WS_G, prevR, prevW,
                                              ws + WS_SIMR, ws + WS_SIMW, ws + WS_SHIFT);
  k_transpose<<<dim3(16, 16, 3), dim3(32, 8), 0, stream>>>(ws + WS_SIMR, ws + WS_SIMW, ws + WS_SHIFT,
                                                           ws + WS_WGRT, ws + WS_WGWT, ws + WS_SHIFTT);
  k_circ<<<dim3(128, 2), 256, 0, stream>>>(ws + WS_WGRT, ws + WS_WGWT, ws + WS_SHIFTT,
                                           ws + WS_GAMMA,
                                           ws + WS_CIRCTR, ws + WS_CIRCTW, ws + WS_CSR, ws + WS_CSW);
  k_finalw<<<dim3(16, 16, 2), dim3(32, 8), 0, stream>>>(ws + WS_CIRCTR, ws + WS_CIRCTW,
                                                        ws + WS_CSR, ws + WS_CSW, out);
  k_readvec<<<dim3(16, 8, 4), 64, 0, stream>>>(ws + WS_CIRCTR, ws + WS_CSR, memory, out);
}

// Round 5
// 179.858 us; speedup vs baseline: 1.3232x; 1.3232x over previous
//
#include <hip/hip_runtime.h>
#include <math.h>

#define N   512
#define M   256
#define A   128
#define HS  512
#define C   512

#define WS_H       0
#define WS_HEADS   262144
#define WS_SIMR    786432
#define WS_SIMW    1048576
#define WS_SHIFT   1310720
#define WS_WGRT    1572864
#define WS_WGWT    1835008
#define WS_SHIFTT  2097152
#define WS_CIRCTR  2359296
#define WS_CIRCTW  2621440
#define WS_MEMT    2883584
#define WS_G       3014656
#define WS_GAMMA   3015168
#define WS_INVM    3015680
#define WS_INVKR   3016192
#define WS_INVKW   3016704
#define WS_CSR     3017216
#define WS_CSW     3017728

#define LD4(p) (*reinterpret_cast<const float4*>(p))
#define LD2(p) (*reinterpret_cast<const float2*>(p))

typedef short bf16x8 __attribute__((ext_vector_type(8)));
typedef float f32x16 __attribute__((ext_vector_type(16)));

struct HiLo { bf16x8 hi, lo; };

__device__ __forceinline__ HiLo split8(const float4 u, const float4 v) {
  const float x[8] = {u.x, u.y, u.z, u.w, v.x, v.y, v.z, v.w};
  union { unsigned int w[4]; bf16x8 v; } H, L;
#pragma unroll
  for (int d = 0; d < 4; ++d) {
    const unsigned int a = __float_as_uint(x[2 * d]);
    const unsigned int b = __float_as_uint(x[2 * d + 1]);
    H.w[d] = (a >> 16) | (b & 0xFFFF0000u);
    const float la = x[2 * d]     - __uint_as_float(a & 0xFFFF0000u);
    const float lb = x[2 * d + 1] - __uint_as_float(b & 0xFFFF0000u);
    L.w[d] = (__float_as_uint(la) >> 16) | (__float_as_uint(lb) & 0xFFFF0000u);
  }
  HiLo r; r.hi = H.v; r.lo = L.v;
  return r;
}

__device__ __forceinline__ f32x16 mm3(const HiLo& a, const HiLo& b, f32x16 acc) {
  acc = __builtin_amdgcn_mfma_f32_32x32x16_bf16(a.hi, b.hi, acc, 0, 0, 0);
  acc = __builtin_amdgcn_mfma_f32_32x32x16_bf16(a.hi, b.lo, acc, 0, 0, 0);
  acc = __builtin_amdgcn_mfma_f32_32x32x16_bf16(a.lo, b.hi, acc, 0, 0, 0);
  return acc;
}

template <int NK>
__device__ __forceinline__ f32x16 mfma_tile(const float* __restrict__ Abase, int lda,
                                            const float* __restrict__ Bbase, int ldb,
                                            int lane) {
  const int m = lane & 31, koff = (lane >> 5) * 8;
  const float* pa = Abase + m * lda + koff;
  const float* pb = Bbase + m * ldb + koff;
  f32x16 acc;
#pragma unroll
  for (int t = 0; t < 16; ++t) acc[t] = 0.0f;
  float4 na0 = LD4(pa), na1 = LD4(pa + 4);
  float4 nb0 = LD4(pb), nb1 = LD4(pb + 4);
#pragma unroll 4
  for (int ks = 0; ks < NK; ++ks) {
    const float4 ca0 = na0, ca1 = na1, cb0 = nb0, cb1 = nb1;
    if (ks + 1 < NK) {
      const int k = (ks + 1) * 16;
      na0 = LD4(pa + k); na1 = LD4(pa + k + 4);
      nb0 = LD4(pb + k); nb1 = LD4(pb + k + 4);
    }
    const HiLo Af = split8(ca0, ca1);
    const HiLo Bf = split8(cb0, cb1);
    acc = mm3(Af, Bf, acc);
  }
  return acc;
}

#define ACC_ROW(t, lane) (((t) & 3) + 8 * ((t) >> 2) + 4 * ((lane) >> 5))

__global__ __launch_bounds__(64) void k_gruh(const float* __restrict__ action,
                                             const float* __restrict__ hidden,
                                             const float* __restrict__ W_ih,
                                             const float* __restrict__ b_ih,
                                             const float* __restrict__ b_hh,
                                             float* __restrict__ h) {
  const int lane = threadIdx.x;
  const int r0 = blockIdx.x * 32, c0 = blockIdx.y * 32;
  const int m = lane & 31, koff = (lane >> 5) * 8;
  const float* pa_act = action + (r0 + m) * 128 + koff;
  const float* pa_hid = hidden + (r0 + m) * 512 + koff;
  const float* pR = W_ih + (c0 + m) * 640 + koff;
  const float* pZ = pR + 512 * 640;
  const float* pN = pZ + 512 * 640;

  f32x16 aR, aZ, aN;
#pragma unroll
  for (int t = 0; t < 16; ++t) { aR[t] = 0.f; aZ[t] = 0.f; aN[t] = 0.f; }

  float4 na0 = LD4(pa_act), na1 = LD4(pa_act + 4);
  float4 nr0 = LD4(pR), nr1 = LD4(pR + 4);
  float4 nz0 = LD4(pZ), nz1 = LD4(pZ + 4);
  float4 nn0 = LD4(pN), nn1 = LD4(pN + 4);
#pragma unroll 4
  for (int ks = 0; ks < 40; ++ks) {
    const float4 ca0 = na0, ca1 = na1;
    const float4 cr0 = nr0, cr1 = nr1, cz0 = nz0, cz1 = nz1, cn0 = nn0, cn1 = nn1;
    if (ks < 39) {
      const int k = (ks + 1) * 16;
      const float* pa = (k < 128) ? (pa_act + k) : (pa_hid + (k - 128));
      na0 = LD4(pa); na1 = LD4(pa + 4);
      nr0 = LD4(pR + k); nr1 = LD4(pR + k + 4);
      nz0 = LD4(pZ + k); nz1 = LD4(pZ + k + 4);
      nn0 = LD4(pN + k); nn1 = LD4(pN + k + 4);
    }
    const HiLo Af = split8(ca0, ca1);
    const HiLo Rf = split8(cr0, cr1);
    const HiLo Zf = split8(cz0, cz1);
    const HiLo Nf = split8(cn0, cn1);
    aR = mm3(Af, Rf, aR);
    aZ = mm3(Af, Zf, aZ);
    aN = mm3(Af, Nf, aN);
  }

  const int col = c0 + m;
  const float br = b_ih[col] + b_hh[col];
  const float bz = b_ih[512 + col] + b_hh[512 + col];
  const float bn = b_ih[1024 + col];
  const float hn = b_hh[1024 + col];
#pragma unroll
  for (int t = 0; t < 16; ++t) {
    const int row = r0 + ACC_ROW(t, lane);
    const float gr = aR[t] + br, gz = aZ[t] + bz, gn = aN[t] + bn;
    const float rr = 1.0f / (1.0f + expf(-gr));
    const float zz = 1.0f / (1.0f + expf(-gz));
    h[row * 512 + col] = (1.0f - zz) * tanhf(gn + rr * hn);
  }
}

__global__ __launch_bounds__(64) void k_heads(const float* __restrict__ h,
                                              const float* __restrict__ W_read, const float* __restrict__ b_read,
                                              const float* __restrict__ W_write, const float* __restrict__ b_write,
                                              const float* __restrict__ W_shift, const float* __restrict__ b_shift,
                                              float* __restrict__ heads) {
  const int lane = threadIdx.x;
  const int r0 = blockIdx.x * 32;
  const int n0 = blockIdx.y * 32;
  const float* W;
  const float* bias;
  if (n0 < 256)      { W = W_read  + n0 * 512;         bias = b_read  + n0; }
  else if (n0 < 512) { W = W_write + (n0 - 256) * 512; bias = b_write + (n0 - 256); }
  else               { W = W_shift + (n0 - 512) * 512; bias = b_shift + (n0 - 512); }

  const f32x16 acc = mfma_tile<32>(h + r0 * 512, 512, W, 512, lane);
  const int col = lane & 31;
  const float bv = bias[col];
#pragma unroll
  for (int t = 0; t < 16; ++t)
    heads[(r0 + ACC_ROW(t, lane)) * 1024 + n0 + col] = acc[t] + bv;
}

__global__ __launch_bounds__(64) void k_ggnorms(const float* __restrict__ h,
                                                const float* __restrict__ W_gate, const float* __restrict__ b_gate,
                                                const float* __restrict__ W_gamma, const float* __restrict__ b_gamma,
                                                const float* __restrict__ memory,
                                                const float* __restrict__ heads,
                                                float* __restrict__ g, float* __restrict__ gamma,
                                                float* __restrict__ invm, float* __restrict__ invkr,
                                                float* __restrict__ invkw) {
  const int r = blockIdx.x, t = threadIdx.x;
  if (r < 512) {
    float ag = 0.f, am = 0.f;
#pragma unroll
    for (int u = 0; u < 8; ++u) {
      const float hv = h[r * 512 + t + 64 * u];
      ag = fmaf(hv, W_gate[t + 64 * u], ag);
      am = fmaf(hv, W_gamma[t + 64 * u], am);
    }
    for (int o = 32; o > 0; o >>= 1) { ag += __shfl_down(ag, o); am += __shfl_down(am, o); }
    if (t == 0) {
      g[r] = 1.0f / (1.0f + expf(-(ag + b_gate[0])));
      const float x = am + b_gamma[0];
      gamma[r] = (x > 0.f) ? (x + log1pf(expf(-x))) : log1pf(expf(x));
    }
    return;
  }
  float ss;
  float* dst;
  if (r < 1024) {
    const float4 v = LD4(memory + (r - 512) * 256 + t * 4);
    ss = v.x * v.x + v.y * v.y + v.z * v.z + v.w * v.w;
    dst = invm + (r - 512);
  } else {
    const int row = (r < 1536) ? (r - 1024) : (r - 1536);
    const int seg = (r < 1536) ? 0 : 256;
    const float4 v = LD4(heads + row * 1024 + seg + t * 4);
    ss = v.x * v.x + v.y * v.y + v.z * v.z + v.w * v.w;
    dst = ((r < 1536) ? invkr : invkw) + row;
  }
  for (int o = 32; o > 0; o >>= 1) ss += __shfl_down(ss, o);
  if (t == 0) *dst = 1.0f / (sqrtf(ss) + 1e-16f);
}

__global__ __launch_bounds__(64) void k_sim(const float* __restrict__ memory,
                                            const float* __restrict__ heads,
                                            float* __restrict__ simR, float* __restrict__ simW) {
  const int lane = threadIdx.x;
  const int i0 = blockIdx.x * 32;
  const int b0 = blockIdx.y * 32;
  const int seg = blockIdx.z ? 256 : 0;
  float* out = blockIdx.z ? simW : simR;
  const f32x16 acc = mfma_tile<16>(memory + i0 * 256, 256,
                                   heads + b0 * 1024 + seg, 1024, lane);
  const int col = lane & 31;
#pragma unroll
  for (int t = 0; t < 16; ++t)
    out[(i0 + ACC_ROW(t, lane)) * 512 + b0 + col] = acc[t];
}

__global__ __launch_bounds__(256) void k_rowsoft(const float* __restrict__ simR, const float* __restrict__ simW,
                                                 const float* __restrict__ heads,
                                                 const float* __restrict__ invm, const float* __restrict__ invkr,
                                                 const float* __restrict__ invkw, const float* __restrict__ g,
                                                 const float* __restrict__ prevR, const float* __restrict__ prevW,
                                                 float* __restrict__ wgr, float* __restrict__ wgw,
                                                 float* __restrict__ shift_nat) {
  __shared__ float red[8];
  const int row = blockIdx.x, mode = blockIdx.y, t = threadIdx.x;
  float v0, v1;
  if (mode == 2) {
    const float2 s = LD2(heads + row * 1024 + 512 + 2 * t);
    v0 = s.x; v1 = s.y;
  } else {
    const float* sim = mode ? simW : simR;
    const float* invk = mode ? invkw : invkr;
    const float2 s = LD2(sim + row * 512 + 2 * t);
    const float sc = invm[row];
    v0 = s.x * sc * invk[2 * t];
    v1 = s.y * sc * invk[2 * t + 1];
  }
  float mx = fmaxf(v0, v1);
  for (int o = 32; o > 0; o >>= 1) mx = fmaxf(mx, __shfl_down(mx, o));
  if ((t & 63) == 0) red[t >> 6] = mx;
  __syncthreads();
  mx = fmaxf(fmaxf(red[0], red[1]), fmaxf(red[2], red[3]));
  const float e0 = expf(v0 - mx), e1 = expf(v1 - mx);
  float s2 = e0 + e1;
  for (int o = 32; o > 0; o >>= 1) s2 += __shfl_down(s2, o);
  if ((t & 63) == 0) red[4 + (t >> 6)] = s2;
  __syncthreads();
  const float S = (red[4] + red[5]) + (red[6] + red[7]);
  const float inv = 1.0f / S;
  const float p0 = e0 * inv, p1 = e1 * inv;
  if (mode == 2) {
    *reinterpret_cast<float2*>(shift_nat + row * 512 + 2 * t) = make_float2(p0, p1);
  } else {
    const float* prev = mode ? prevW : prevR;
    float* outw = mode ? wgw : wgr;
    const float gv = g[row];
    const float2 pr = LD2(prev + row * 512 + 2 * t);
    *reinterpret_cast<float2*>(outw + row * 512 + 2 * t) =
        make_float2(gv * p0 + (1.0f - gv) * pr.x, gv * p1 + (1.0f - gv) * pr.y);
  }
}

__global__ __launch_bounds__(256) void k_transpose(const float* __restrict__ wgr, const float* __restrict__ wgw,
                                                   const float* __restrict__ shift_nat,
                                                   float* __restrict__ wgrT, float* __restrict__ wgwT,
                                                   float* __restrict__ shiftT) {
  __shared__ float tile[32][33];
  const int z = blockIdx.z;
  const float* src = (z == 0) ? wgr : (z == 1) ? wgw : shift_nat;
  float* dst = (z == 0) ? wgrT : (z == 1) ? wgwT : shiftT;
  const int bx = blockIdx.x, by = blockIdx.y, tx = threadIdx.x, ty = threadIdx.y;
#pragma unroll
  for (int k2 = 0; k2 < 4; ++k2)
    tile[ty + 8 * k2][tx] = src[(by * 32 + ty + 8 * k2) * 512 + bx * 32 + tx];
  __syncthreads();
#pragma unroll
  for (int k2 = 0; k2 < 4; ++k2)
    dst[(bx * 32 + ty + 8 * k2) * 512 + by * 32 + tx] = tile[tx][ty + 8 * k2];
}

__global__ __launch_bounds__(256) void k_memT(const float* __restrict__ mem, float* __restrict__ memT) {
  __shared__ float tile[32][33];
  const int bx = blockIdx.x, by = blockIdx.y, tx = threadIdx.x, ty = threadIdx.y;
#pragma unroll
  for (int k2 = 0; k2 < 4; ++k2)
    tile[ty + 8 * k2][tx] = mem[(by * 32 + ty + 8 * k2) * 256 + bx * 32 + tx];
  __syncthreads();
#pragma unroll
  for (int k2 = 0; k2 < 4; ++k2)
    memT[(bx * 32 + ty + 8 * k2) * 512 + by * 32 + tx] = tile[tx][ty + 8 * k2];
}

__global__ __launch_bounds__(256) void k_circ(const float* __restrict__ wgrT, const float* __restrict__ wgwT,
                                              const float* __restrict__ shiftT,
                                              const float* __restrict__ gamma,
                                              float* __restrict__ circTR, float* __restrict__ circTW,
                                              float* __restrict__ csumR, float* __restrict__ csumW) {
  __shared__ float ls[4][1600];
  const int wid = threadIdx.x >> 6, lane = threadIdx.x & 63;
  const int b = blockIdx.x * 4 + wid;
  const float* wsrc = (blockIdx.y ? wgwT : wgrT) + b * 512;
  const float* ssrc = shiftT + b * 512;
  float* out = (blockIdx.y ? circTW : circTR) + b * 512;
  float* cs = blockIdx.y ? csumW : csumR;
  float* wl = ls[wid];
  float* sl = ls[wid] + 1056;

#pragma unroll
  for (int u = 0; u < 8; ++u) {
    const int k = lane + 64 * u;
    const float v = wsrc[k];
    wl[k + (k >> 5)] = v;
    const int k2 = k + 512;
    wl[k2 + (k2 >> 5)] = v;
    sl[k] = ssrc[k];
  }
  __syncthreads();

  const int i0 = lane * 8;
  float acc[8] = {};
  float win[8];
#pragma unroll
  for (int q = 0; q < 8; ++q) {
    const int a0 = i0 + 512 + q;
    win[q] = wl[a0 + (a0 >> 5)];
  }
  for (int jb = 0; jb < 512; jb += 8) {
    const float4 sA = LD4(&sl[jb]);
    const float4 sB = LD4(&sl[jb + 4]);
    const float sv[8] = {sA.x, sA.y, sA.z, sA.w, sB.x, sB.y, sB.z, sB.w};
#pragma unroll
    for (int u = 0; u < 8; ++u) {
      const float s = sv[u];
#pragma unroll
      for (int t = 0; t < 8; ++t) acc[t] = fmaf(win[(t - u) & 7], s, acc[t]);
      const int na = i0 + 511 - (jb + u);
      win[(7 - u) & 7] = wl[na + (na >> 5)];
    }
  }
  const float4 gm0 = LD4(gamma + i0);
  const float4 gm1 = LD4(gamma + i0 + 4);
  const float ge[8] = {gm0.x, gm0.y, gm0.z, gm0.w, gm1.x, gm1.y, gm1.z, gm1.w};
  float p[8];
  float local = 0.f;
#pragma unroll
  for (int q = 0; q < 8; ++q) { p[q] = powf(acc[q], ge[q]); local += p[q]; }
  *reinterpret_cast<float4*>(out + i0) = make_float4(p[0], p[1], p[2], p[3]);
  *reinterpret_cast<float4*>(out + i0 + 4) = make_float4(p[4], p[5], p[6], p[7]);
  for (int o = 32; o > 0; o >>= 1) local += __shfl_down(local, o);
  if (lane == 0) cs[b] = local;
}

__global__ __launch_bounds__(256) void k_finalw(const float* __restrict__ circTR, const float* __restrict__ circTW,
                                                const float* __restrict__ csumR, const float* __restrict__ csumW,
                                                float* __restrict__ d_out) {
  __shared__ float tile[32][33];
  const int z = blockIdx.z;
  const float* src = z ? circTW : circTR;
  const float* cs = z ? csumW : csumR;
  float* dst = d_out + 131072 + z * 262144;
  const int bx = blockIdx.x, by = blockIdx.y, tx = threadIdx.x, ty = threadIdx.y;
#pragma unroll
  for (int k2 = 0; k2 < 4; ++k2) {
    const int r = by * 32 + ty + 8 * k2;
    tile[ty + 8 * k2][tx] = src[r * 512 + bx * 32 + tx] * (1.0f / cs[r]);
  }
  __syncthreads();
#pragma unroll
  for (int k2 = 0; k2 < 4; ++k2)
    dst[(bx * 32 + ty + 8 * k2) * 512 + by * 32 + tx] = tile[tx][ty + 8 * k2];
}

__global__ __launch_bounds__(64) void k_readvec(const float* __restrict__ rw,
                                                const float* __restrict__ memT,
                                                float* __restrict__ rv) {
  const int lane = threadIdx.x;
  const int i0 = blockIdx.x * 32;
  const int m0 = blockIdx.y * 32;
  const f32x16 acc = mfma_tile<32>(rw + i0 * 512, 512, memT + m0 * 512, 512, lane);
  const int col = lane & 31;
#pragma unroll
  for (int t = 0; t < 16; ++t)
    rv[(i0 + ACC_ROW(t, lane)) * 256 + m0 + col] = acc[t];
}

extern "C" void kernel_launch(void* const* d_in, const int* in_sizes, int n_in,
                              void* d_out, int out_size, void* d_ws, size_t ws_size,
                              hipStream_t stream) {
  const float* action  = (const float*)d_in[0];
  const float* hidden  = (const float*)d_in[1];
  const float* prevR   = (const float*)d_in[2];
  const float* prevW   = (const float*)d_in[3];
  const float* memory  = (const float*)d_in[4];
  const float* W_ih    = (const float*)d_in[5];
  const float* b_ih    = (const float*)d_in[7];
  const float* b_hh    = (const float*)d_in[8];
  const float* W_read  = (const float*)d_in[9];
  const float* b_read  = (const float*)d_in[10];
  const float* W_write = (const float*)d_in[11];
  const float* b_write = (const float*)d_in[12];
  const float* W_shift = (const float*)d_in[13];
  const float* b_shift = (const float*)d_in[14];
  const float* W_gamma = (const float*)d_in[15];
  const float* b_gamma = (const float*)d_in[16];
  const float* W_gate  = (const float*)d_in[17];
  const float* b_gate  = (const float*)d_in[18];

  float* ws = (float*)d_ws;
  float* out = (float*)d_out;

  k_memT<<<dim3(8, 16), dim3(32, 8), 0, stream>>>(memory, ws + WS_MEMT);
  k_gruh<<<dim3(16, 16), 64, 0, stream>>>(action, hidden, W_ih, b_ih, b_hh, ws + WS_H);
  k_heads<<<dim3(16, 32), 64, 0, stream>>>(ws + WS_H, W_read, b_read, W_write, b_write,
                                           W_shift, b_shift, ws + WS_HEADS);
  k_ggnorms<<<2048, 64, 0, stream>>>(ws + WS_H, W_gate, b_gate, W_gamma, b_gamma,
                                     memory, ws + WS_HEADS,
                                     ws + WS_G, ws + WS_GAMMA,
                                     ws + WS_INVM, ws + WS_INVKR, ws + WS_INVKW);
  k_sim<<<dim3(16, 16, 2), 64, 0, stream>>>(memory, ws + WS_HEADS, ws + WS_SIMR, ws + WS_SIMW);
  k_rowsoft<<<dim3(512, 3), 256, 0, stream>>>(ws + WS_SIMR, ws + WS_SIMW, ws + WS_HEADS,
                                              ws + WS_INVM, ws + WS_INVKR, ws + WS_INVKW,
                                              ws + WS_G, prevR, prevW,
                                              ws + WS_SIMR, ws + WS_SIMW, ws + WS_SHIFT);
  k_transpose<<<dim3(16, 16, 3), dim3(32, 8), 0, stream>>>(ws + WS_SIMR, ws + WS_SIMW, ws + WS_SHIFT,
                                                           ws + WS_WGRT, ws + WS_WGWT, ws + WS_SHIFTT);
  k_circ<<<dim3(128, 2), 256, 0, stream>>>(ws + WS_WGRT, ws + WS_WGWT, ws + WS_SHIFTT,
                                           ws + WS_GAMMA,
                                           ws + WS_CIRCTR, ws + WS_CIRCTW,
                                           ws + WS_CSR, ws + WS_CSW);
  k_finalw<<<dim3(16, 16, 2), dim3(32, 8), 0, stream>>>(ws + WS_CIRCTR, ws + WS_CIRCTW,
                                                        ws + WS_CSR, ws + WS_CSW, out);
  k_readvec<<<dim3(16, 8), 64, 0, stream>>>(out + 131072, ws + WS_MEMT, out);
}